// Round 1
// baseline (1006.394 us; speedup 1.0000x reference)
//
#include <hip/hip_runtime.h>
#include <math.h>

#define D 128
#define NSUBJ 16
#define MARGIN 0.8f
#define EPS 1e-6f

// Kernel 1: per-row squared norm + bucket rows by subject.
__global__ void prep_kernel(const float* __restrict__ emb, const int* __restrict__ sbj,
                            float* __restrict__ sq, int* __restrict__ counts,
                            int* __restrict__ lists, int B) {
    int i = blockIdx.x * blockDim.x + threadIdx.x;
    if (i >= B) return;
    const float4* row = (const float4*)(emb + (size_t)i * D);
    float acc = 0.f;
#pragma unroll
    for (int d = 0; d < D / 4; ++d) {
        float4 a = row[d];
        acc = fmaf(a.x, a.x, acc);
        acc = fmaf(a.y, a.y, acc);
        acc = fmaf(a.z, a.z, acc);
        acc = fmaf(a.w, a.w, acc);
    }
    sq[i] = acc;
    int s = sbj[i];
    int pos = atomicAdd(&counts[s], 1);
    lists[s * B + pos] = i;
}

// Kernel 2: one block per row i. Scan i's subject group for hardest positive
// (max d2, same label, j!=i) and hardest negative (min d2, diff label), then
// compute the two triplet distances and accumulate the hinge loss.
__global__ __launch_bounds__(256) void triplet_kernel(
        const float* __restrict__ emb, const int* __restrict__ labels,
        const int* __restrict__ sbj, const float* __restrict__ sq,
        const int* __restrict__ counts, const int* __restrict__ lists,
        float* __restrict__ loss_sum, int* __restrict__ valid_cnt, int B) {
    int i = blockIdx.x;
    int t = threadIdx.x;
    __shared__ float ei[D];
    __shared__ float rv[256];
    __shared__ int   ri[256];
    __shared__ int   s_pidx, s_nidx;

    if (t < D / 4) ((float4*)ei)[t] = ((const float4*)(emb + (size_t)i * D))[t];
    int s = sbj[i];
    int l = labels[i];
    int n = counts[s];
    const int* grp = lists + (size_t)s * B;
    __syncthreads();

    // Per-thread scan. d2 relative value: sq[j] - 2*dot (sq[i] constant dropped).
    float bestP = -INFINITY; int pIdx = -1;
    float bestN =  INFINITY; int nIdx = -1;
    for (int k = t; k < n; k += 256) {
        int j = grp[k];
        const float4* bj = (const float4*)(emb + (size_t)j * D);
        float acc = 0.f;
#pragma unroll
        for (int d = 0; d < D / 4; ++d) {
            float4 a = ((float4*)ei)[d];
            float4 b = bj[d];
            acc = fmaf(a.x, b.x, acc);
            acc = fmaf(a.y, b.y, acc);
            acc = fmaf(a.z, b.z, acc);
            acc = fmaf(a.w, b.w, acc);
        }
        float v = sq[j] - 2.f * acc;
        if (labels[j] == l) {
            // tie-break: smallest original index (jnp.argmax first-occurrence).
            // (unsigned)-1 acts as +inf so the sentinel always loses.
            if (j != i && (v > bestP || (v == bestP && (unsigned)j < (unsigned)pIdx))) {
                bestP = v; pIdx = j;
            }
        } else {
            if (v < bestN || (v == bestN && (unsigned)j < (unsigned)nIdx)) {
                bestN = v; nIdx = j;
            }
        }
    }

    // Block argmax reduction (positive).
    rv[t] = bestP; ri[t] = pIdx;
    __syncthreads();
    for (int off = 128; off > 0; off >>= 1) {
        if (t < off) {
            float ov = rv[t + off]; int oi = ri[t + off];
            if (ov > rv[t] || (ov == rv[t] && (unsigned)oi < (unsigned)ri[t])) {
                rv[t] = ov; ri[t] = oi;
            }
        }
        __syncthreads();
    }
    if (t == 0) s_pidx = ri[0];
    __syncthreads();

    // Block argmin reduction (negative).
    rv[t] = bestN; ri[t] = nIdx;
    __syncthreads();
    for (int off = 128; off > 0; off >>= 1) {
        if (t < off) {
            float ov = rv[t + off]; int oi = ri[t + off];
            if (ov < rv[t] || (ov == rv[t] && (unsigned)oi < (unsigned)ri[t])) {
                rv[t] = ov; ri[t] = oi;
            }
        }
        __syncthreads();
    }
    if (t == 0) s_nidx = ri[0];
    __syncthreads();

    int p  = s_pidx;
    int nn = s_nidx;
    bool valid = (p >= 0) && (nn >= 0);

    // Cooperative distance computation: lower 128 threads -> dap^2,
    // upper 128 threads -> dan^2 (torch pairwise_distance adds EPS to diff).
    float c = 0.f;
    if (valid) {
        if (t < D) {
            float dlt = ei[t] - emb[(size_t)p * D + t] + EPS;
            c = dlt * dlt;
        } else {
            int d = t - D;
            float dlt = ei[d] - emb[(size_t)nn * D + d] + EPS;
            c = dlt * dlt;
        }
    }
    rv[t] = c;
    __syncthreads();
    for (int off = 64; off > 0; off >>= 1) {
        if ((t & 127) < off) rv[t] += rv[t + off];
        __syncthreads();
    }
    if (t == 0 && valid) {
        float dap = sqrtf(rv[0]);
        float dan = sqrtf(rv[D]);
        float per = fmaxf(dap - dan + MARGIN, 0.f);
        atomicAdd(loss_sum, per);
        atomicAdd(valid_cnt, 1);
    }
}

__global__ void finalize_kernel(const float* __restrict__ loss_sum,
                                const int* __restrict__ valid_cnt,
                                float* __restrict__ out) {
    float sum = *loss_sum;
    int cnt = *valid_cnt;
    out[0] = (cnt > 0) ? (sum / (float)cnt) : 0.0f;
}

extern "C" void kernel_launch(void* const* d_in, const int* in_sizes, int n_in,
                              void* d_out, int out_size, void* d_ws, size_t ws_size,
                              hipStream_t stream) {
    const float* emb    = (const float*)d_in[0];
    const int*   labels = (const int*)d_in[1];
    const int*   sbj    = (const int*)d_in[2];
    float*       out    = (float*)d_out;
    int B = in_sizes[1];   // 8192

    // Workspace layout (re-poisoned to 0xAA before every launch -> must memset):
    //   [0,64)    : int counts[16]
    //   [64,68)   : float loss_sum
    //   [72,76)   : int valid_cnt
    //   [128, 128+4B)          : float sq[B]
    //   [128+4B, 128+4B+64B*4) : int lists[16][B]
    char*  ws        = (char*)d_ws;
    int*   counts    = (int*)ws;
    float* loss_sum  = (float*)(ws + 64);
    int*   valid_cnt = (int*)(ws + 72);
    float* sq        = (float*)(ws + 128);
    int*   lists     = (int*)(ws + 128 + (size_t)B * sizeof(float));

    hipMemsetAsync(ws, 0, 128, stream);
    prep_kernel<<<(B + 255) / 256, 256, 0, stream>>>(emb, sbj, sq, counts, lists, B);
    triplet_kernel<<<B, 256, 0, stream>>>(emb, labels, sbj, sq, counts, lists,
                                          loss_sum, valid_cnt, B);
    finalize_kernel<<<1, 1, 0, stream>>>(loss_sum, valid_cnt, out);
}

// Round 2
// 170.129 us; speedup vs baseline: 5.9155x; 5.9155x over previous
//
#include <hip/hip_runtime.h>
#include <math.h>
#include <limits.h>

#define D 128
#define NF4 (D/4)      // 32 float4 per embedding row
#define NSUBJ 16
#define MARGIN 0.8f
#define EPS 1e-6f
#define TI 32          // I-tile rows per block
#define TJ 64          // J-tile cols per iteration
#define LDT 33         // LDS tile stride in float4 (33*16B=528B -> +4 bank shift/row)

// Kernel 1: per-row squared norm + bucket rows by subject.
__global__ void prep_kernel(const float* __restrict__ emb, const int* __restrict__ sbj,
                            float* __restrict__ sq, int* __restrict__ counts,
                            int* __restrict__ lists, int B) {
    int i = blockIdx.x * blockDim.x + threadIdx.x;
    if (i >= B) return;
    const float4* row = (const float4*)(emb + (size_t)i * D);
    float acc = 0.f;
#pragma unroll
    for (int d = 0; d < NF4; ++d) {
        float4 a = row[d];
        acc = fmaf(a.x, a.x, acc);
        acc = fmaf(a.y, a.y, acc);
        acc = fmaf(a.z, a.z, acc);
        acc = fmaf(a.w, a.w, acc);
    }
    sq[i] = acc;
    int s = sbj[i];
    int pos = atomicAdd(&counts[s], 1);
    lists[s * B + pos] = i;
}

// Kernel 2: tiled within-group distance + fused argmax/argmin + triplet loss.
// Block (x=tile, y=subject) owns rows [i0, i0+TI) of subject y's group list.
__global__ __launch_bounds__(256, 2) void triplet_tiled(
        const float* __restrict__ emb, const int* __restrict__ labels,
        const float* __restrict__ sq, const int* __restrict__ counts,
        const int* __restrict__ lists,
        float* __restrict__ loss_sum, int* __restrict__ valid_cnt, int B) {
    const int s  = blockIdx.y;
    const int n  = counts[s];
    const int i0 = blockIdx.x * TI;
    if (i0 >= n) return;                       // block-uniform early exit
    const int nrows = min(TI, n - i0);
    const int* grp = lists + (size_t)s * B;
    const int t = threadIdx.x;

    __shared__ float4 As[TI][LDT];             // 16.9 KB  anchor tile
    __shared__ float4 Bs[TJ][LDT];             // 33.8 KB  streaming tile
    __shared__ float  sqj[TJ];
    __shared__ int    labj[TJ], jidx[TJ];
    __shared__ int    gi[TI], labi[TI];
    __shared__ float  rP[TI][16]; __shared__ int rPi[TI][16];
    __shared__ float  rN[TI][16]; __shared__ int rNi[TI][16];
    __shared__ int    selP[TI], selN[TI];
    __shared__ float  perRow[TI]; __shared__ int validRow[TI];

    // ---- load I-tile (coalesced: 32 consecutive lanes stream one row) ----
    {
        int lin = t;
#pragma unroll
        for (int it = 0; it < TI * NF4 / 256; ++it, lin += 256) {
            int r = lin >> 5, c = lin & 31;
            int g = grp[i0 + min(r, nrows - 1)];   // pad rows replicate last valid
            As[r][c] = ((const float4*)(emb + (size_t)g * D))[c];
        }
    }
    if (t < TI) {
        if (t < nrows) { int g = grp[i0 + t]; gi[t] = g; labi[t] = labels[g]; }
        else           { gi[t] = -1; labi[t] = INT_MIN; }
    }

    const int rg = t >> 4;          // 0..15 -> rows rg*2, rg*2+1
    const int cg = t & 15;          // 0..15 -> cols cg, 16+cg, 32+cg, 48+cg
    const int r0 = rg * 2, r1 = r0 + 1;

    float bP0 = -INFINITY, bP1 = -INFINITY; int iP0 = -1, iP1 = -1;
    float bN0 =  INFINITY, bN1 =  INFINITY; int iN0 = -1, iN1 = -1;

    for (int j0 = 0; j0 < n; j0 += TJ) {
        const int ncols = min(TJ, n - j0);
        __syncthreads();                        // previous tile fully consumed
        {
            int lin = t;
#pragma unroll
            for (int it = 0; it < TJ * NF4 / 256; ++it, lin += 256) {
                int r = lin >> 5, c = lin & 31;
                int g = grp[j0 + min(r, ncols - 1)];
                Bs[r][c] = ((const float4*)(emb + (size_t)g * D))[c];
            }
        }
        if (t < TJ) {
            if (t < ncols) {
                int g = grp[j0 + t];
                jidx[t] = g; labj[t] = labels[g]; sqj[t] = sq[g];
            } else {
                jidx[t] = -1; labj[t] = INT_MIN; sqj[t] = 0.f;
            }
        }
        __syncthreads();

        float a00 = 0.f, a01 = 0.f, a02 = 0.f, a03 = 0.f;
        float a10 = 0.f, a11 = 0.f, a12 = 0.f, a13 = 0.f;
#pragma unroll 8
        for (int k = 0; k < NF4; ++k) {
            float4 x0 = As[r0][k], x1 = As[r1][k];
            float4 b0 = Bs[cg][k];
            float4 b1 = Bs[16 + cg][k];
            float4 b2 = Bs[32 + cg][k];
            float4 b3 = Bs[48 + cg][k];
            a00 = fmaf(x0.x,b0.x,fmaf(x0.y,b0.y,fmaf(x0.z,b0.z,fmaf(x0.w,b0.w,a00))));
            a01 = fmaf(x0.x,b1.x,fmaf(x0.y,b1.y,fmaf(x0.z,b1.z,fmaf(x0.w,b1.w,a01))));
            a02 = fmaf(x0.x,b2.x,fmaf(x0.y,b2.y,fmaf(x0.z,b2.z,fmaf(x0.w,b2.w,a02))));
            a03 = fmaf(x0.x,b3.x,fmaf(x0.y,b3.y,fmaf(x0.z,b3.z,fmaf(x0.w,b3.w,a03))));
            a10 = fmaf(x1.x,b0.x,fmaf(x1.y,b0.y,fmaf(x1.z,b0.z,fmaf(x1.w,b0.w,a10))));
            a11 = fmaf(x1.x,b1.x,fmaf(x1.y,b1.y,fmaf(x1.z,b1.z,fmaf(x1.w,b1.w,a11))));
            a12 = fmaf(x1.x,b2.x,fmaf(x1.y,b2.y,fmaf(x1.z,b2.z,fmaf(x1.w,b2.w,a12))));
            a13 = fmaf(x1.x,b3.x,fmaf(x1.y,b3.y,fmaf(x1.z,b3.z,fmaf(x1.w,b3.w,a13))));
        }

        const int li0 = labi[r0], li1 = labi[r1];
        const int g0  = gi[r0],  g1  = gi[r1];
#define UPD(COL, AV0, AV1)                                                          \
        {                                                                           \
            int jc = (COL); int jj = jidx[jc];                                      \
            if (jj >= 0) {                                                          \
                int lj = labj[jc]; float sv = sqj[jc];                              \
                float v0 = sv - 2.f * (AV0);                                        \
                float v1 = sv - 2.f * (AV1);                                        \
                if (lj == li0) {                                                    \
                    if (jj != g0 && (v0 > bP0 ||                                    \
                        (v0 == bP0 && (unsigned)jj < (unsigned)iP0))) {             \
                        bP0 = v0; iP0 = jj; }                                       \
                } else if (v0 < bN0 ||                                              \
                        (v0 == bN0 && (unsigned)jj < (unsigned)iN0)) {              \
                    bN0 = v0; iN0 = jj; }                                           \
                if (lj == li1) {                                                    \
                    if (jj != g1 && (v1 > bP1 ||                                    \
                        (v1 == bP1 && (unsigned)jj < (unsigned)iP1))) {             \
                        bP1 = v1; iP1 = jj; }                                       \
                } else if (v1 < bN1 ||                                              \
                        (v1 == bN1 && (unsigned)jj < (unsigned)iN1)) {              \
                    bN1 = v1; iN1 = jj; }                                           \
            }                                                                       \
        }
        UPD(cg,      a00, a10)
        UPD(16 + cg, a01, a11)
        UPD(32 + cg, a02, a12)
        UPD(48 + cg, a03, a13)
#undef UPD
    }

    // ---- per-row reduction over the 16 col-threads ----
    rP[r0][cg] = bP0; rPi[r0][cg] = iP0; rP[r1][cg] = bP1; rPi[r1][cg] = iP1;
    rN[r0][cg] = bN0; rNi[r0][cg] = iN0; rN[r1][cg] = bN1; rNi[r1][cg] = iN1;
    __syncthreads();
    if (t < TI) {
        float bp = -INFINITY; int ip = -1;
        float bn =  INFINITY; int in_ = -1;
#pragma unroll
        for (int c = 0; c < 16; ++c) {
            float v = rP[t][c]; int ii = rPi[t][c];
            if (ii >= 0 && (v > bp || (v == bp && (unsigned)ii < (unsigned)ip))) {
                bp = v; ip = ii;
            }
            float w = rN[t][c]; int jj = rNi[t][c];
            if (jj >= 0 && (w < bn || (w == bn && (unsigned)jj < (unsigned)in_))) {
                bn = w; in_ = jj;
            }
        }
        selP[t] = ip; selN[t] = in_;
    }
    __syncthreads();

    // ---- distance phase: 8 threads per row compute dap^2 / dan^2 ----
    {
        int row = t >> 3, u = t & 7;
        float sump = 0.f, sumn = 0.f;
        int p = selP[row], q = selN[row];
        bool valid = (row < nrows) && (p >= 0) && (q >= 0);
        if (valid) {
            const float4* ep = (const float4*)(emb + (size_t)p * D);
            const float4* en = (const float4*)(emb + (size_t)q * D);
#pragma unroll
            for (int z = 0; z < 4; ++z) {
                int c = u * 4 + z;
                float4 ai = As[row][c];
                float4 vp = ep[c], vn = en[c];
                float d;
                d = ai.x - vp.x + EPS; sump = fmaf(d, d, sump);
                d = ai.y - vp.y + EPS; sump = fmaf(d, d, sump);
                d = ai.z - vp.z + EPS; sump = fmaf(d, d, sump);
                d = ai.w - vp.w + EPS; sump = fmaf(d, d, sump);
                d = ai.x - vn.x + EPS; sumn = fmaf(d, d, sumn);
                d = ai.y - vn.y + EPS; sumn = fmaf(d, d, sumn);
                d = ai.z - vn.z + EPS; sumn = fmaf(d, d, sumn);
                d = ai.w - vn.w + EPS; sumn = fmaf(d, d, sumn);
            }
        }
#pragma unroll
        for (int off = 4; off > 0; off >>= 1) {
            sump += __shfl_down(sump, off, 8);
            sumn += __shfl_down(sumn, off, 8);
        }
        if (u == 0) {
            perRow[row]   = valid ? fmaxf(sqrtf(sump) - sqrtf(sumn) + MARGIN, 0.f) : 0.f;
            validRow[row] = valid ? 1 : 0;
        }
    }
    __syncthreads();
    if (t == 0) {
        float ssum = 0.f; int c = 0;
#pragma unroll
        for (int r = 0; r < TI; ++r) { ssum += perRow[r]; c += validRow[r]; }
        if (c > 0) { atomicAdd(loss_sum, ssum); atomicAdd(valid_cnt, c); }
    }
}

__global__ void finalize_kernel(const float* __restrict__ loss_sum,
                                const int* __restrict__ valid_cnt,
                                float* __restrict__ out) {
    float sum = *loss_sum;
    int cnt = *valid_cnt;
    out[0] = (cnt > 0) ? (sum / (float)cnt) : 0.0f;
}

extern "C" void kernel_launch(void* const* d_in, const int* in_sizes, int n_in,
                              void* d_out, int out_size, void* d_ws, size_t ws_size,
                              hipStream_t stream) {
    const float* emb    = (const float*)d_in[0];
    const int*   labels = (const int*)d_in[1];
    const int*   sbj    = (const int*)d_in[2];
    float*       out    = (float*)d_out;
    int B = in_sizes[1];   // 8192

    // Workspace layout (re-poisoned to 0xAA before every launch -> must memset):
    //   [0,64)    : int counts[16]
    //   [64,68)   : float loss_sum
    //   [72,76)   : int valid_cnt
    //   [128, 128+4B)          : float sq[B]
    //   [128+4B, ...)          : int lists[16][B]
    char*  ws        = (char*)d_ws;
    int*   counts    = (int*)ws;
    float* loss_sum  = (float*)(ws + 64);
    int*   valid_cnt = (int*)(ws + 72);
    float* sq        = (float*)(ws + 128);
    int*   lists     = (int*)(ws + 128 + (size_t)B * sizeof(float));

    hipMemsetAsync(ws, 0, 128, stream);
    prep_kernel<<<(B + 255) / 256, 256, 0, stream>>>(emb, sbj, sq, counts, lists, B);
    dim3 grid((B + TI - 1) / TI, NSUBJ);
    triplet_tiled<<<grid, 256, 0, stream>>>(emb, labels, sq, counts, lists,
                                            loss_sum, valid_cnt, B);
    finalize_kernel<<<1, 1, 0, stream>>>(loss_sum, valid_cnt, out);
}

// Round 3
// 119.899 us; speedup vs baseline: 8.3937x; 1.4189x over previous
//
#include <hip/hip_runtime.h>
#include <math.h>
#include <limits.h>

#define D 128
#define NF4 32         // float4 per row
#define NSUBJ 16
#define MARGIN 0.8f
#define EPS 1e-6f
#define TI 32          // i-rows per block tile
#define TJ 64          // j-cols per streamed tile
#define GX 32          // grid.x (i-tile stripes; loop covers pathological groups)
#define LSTRIDE 136    // LDS row stride in bf16 (128 + 8 pad -> <=2-way bank alias)

typedef __attribute__((ext_vector_type(8))) short bf16x8;
typedef __attribute__((ext_vector_type(4))) float f32x4;

__device__ __forceinline__ short f2bf(float f) {
    union { float f; unsigned u; } v; v.f = f;
    unsigned r = v.u + 0x7FFF + ((v.u >> 16) & 1);   // RNE
    return (short)(r >> 16);
}

// Kernel 1: per-row squared norm + bucket rows by subject (LDS histogram,
// 16 global atomics per block instead of 8192 contended ones).
__global__ __launch_bounds__(256) void prep_kernel(
        const float* __restrict__ emb, const int* __restrict__ sbj,
        float* __restrict__ sq, int* __restrict__ counts,
        int* __restrict__ lists, int B) {
    __shared__ int cnt[NSUBJ], base[NSUBJ];
    int t = threadIdx.x;
    int i = blockIdx.x * 256 + t;
    if (t < NSUBJ) cnt[t] = 0;
    __syncthreads();
    float acc = 0.f; int s = 0, mypos = 0;
    if (i < B) {
        const float4* row = (const float4*)(emb + (size_t)i * D);
#pragma unroll
        for (int d = 0; d < NF4; ++d) {
            float4 a = row[d];
            acc = fmaf(a.x, a.x, acc); acc = fmaf(a.y, a.y, acc);
            acc = fmaf(a.z, a.z, acc); acc = fmaf(a.w, a.w, acc);
        }
        sq[i] = acc;
        s = sbj[i];
        mypos = atomicAdd(&cnt[s], 1);
    }
    __syncthreads();
    if (t < NSUBJ) base[t] = atomicAdd(&counts[t], cnt[t]);
    __syncthreads();
    if (i < B) lists[s * B + base[s] + mypos] = i;
}

// Kernel 2: per-group Gram via bf16 MFMA (16x16x32, gemm_bt layout) fused
// with hardest-positive/negative selection; exact fp32 distances at the end.
__global__ __launch_bounds__(256) void triplet_mfma(
        const float* __restrict__ emb, const int* __restrict__ labels,
        const float* __restrict__ sq, const int* __restrict__ counts,
        const int* __restrict__ lists,
        float* __restrict__ loss_sum, int* __restrict__ valid_cnt, int B) {
    const int s = blockIdx.y;
    const int n = counts[s];
    const int* grp = lists + (size_t)s * B;
    const int t = threadIdx.x;

    __shared__ __align__(16) short As[TI][LSTRIDE];   // 8.7 KB
    __shared__ __align__(16) short Bs[TJ][LSTRIDE];   // 17.4 KB
    __shared__ float sqj[TJ];
    __shared__ int   labj[TJ], jidx[TJ];
    __shared__ int   gi[TI], labi[TI];
    __shared__ float svP[TI][2]; __shared__ int siP[TI][2];
    __shared__ float svN[TI][2]; __shared__ int siN[TI][2];
    __shared__ int   selP[TI], selN[TI];
    __shared__ float perRow[TI]; __shared__ int validRow[TI];

    const int lane  = t & 63;
    const int w     = t >> 6;       // wave 0..3
    const int c     = lane & 15;    // frag row/col index (m or n)
    const int q     = lane >> 4;    // quad
    const int isub  = w >> 1;       // which 16-row half of the i-tile
    const int jhalf = w & 1;        // which 32-col half of the j-tile
    const int jb0   = jhalf * 32;

    float blockSum = 0.f; int blockCnt = 0;

    for (int i0 = blockIdx.x * TI; i0 < n; i0 += GX * TI) {
        const int nrows = min(TI, n - i0);
        __syncthreads();                       // prior iteration's LDS consumers
        // ---- stage A tile: fp32 -> bf16, coalesced ----
        {
            int lin = t;
#pragma unroll
            for (int it = 0; it < (TI * NF4) / 256; ++it, lin += 256) {
                int r = lin >> 5, c4 = lin & 31;
                int g = grp[i0 + min(r, nrows - 1)];
                float4 a = ((const float4*)(emb + (size_t)g * D))[c4];
                short4 pk; pk.x = f2bf(a.x); pk.y = f2bf(a.y);
                pk.z = f2bf(a.z); pk.w = f2bf(a.w);
                *(short4*)&As[r][c4 * 4] = pk;
            }
        }
        if (t < TI) {
            if (t < nrows) { int g = grp[i0 + t]; gi[t] = g; labi[t] = labels[g]; }
            else           { gi[t] = -1; labi[t] = INT_MIN; }
        }
        __syncthreads();

        // per-lane row meta + A-fragments hoisted out of the j-loop
        int li[4], gI[4];
#pragma unroll
        for (int r = 0; r < 4; ++r) {
            int row = isub * 16 + q * 4 + r;
            li[r] = labi[row]; gI[r] = gi[row];
        }
        bf16x8 afr[4];
#pragma unroll
        for (int st = 0; st < 4; ++st)
            afr[st] = *(const bf16x8*)&As[isub * 16 + c][st * 32 + q * 8];

        float vP[4], vN[4]; int iP[4], iN[4];
#pragma unroll
        for (int r = 0; r < 4; ++r) {
            vP[r] = -INFINITY; iP[r] = -1;
            vN[r] =  INFINITY; iN[r] = -1;
        }

        for (int j0 = 0; j0 < n; j0 += TJ) {
            const int ncols = min(TJ, n - j0);
            // ---- stage B tile ----
            {
                int lin = t;
#pragma unroll
                for (int it = 0; it < (TJ * NF4) / 256; ++it, lin += 256) {
                    int r = lin >> 5, c4 = lin & 31;
                    int g = grp[j0 + min(r, ncols - 1)];
                    float4 a = ((const float4*)(emb + (size_t)g * D))[c4];
                    short4 pk; pk.x = f2bf(a.x); pk.y = f2bf(a.y);
                    pk.z = f2bf(a.z); pk.w = f2bf(a.w);
                    *(short4*)&Bs[r][c4 * 4] = pk;
                }
            }
            if (t < TJ) {
                if (t < ncols) {
                    int g = grp[j0 + t];
                    jidx[t] = g; labj[t] = labels[g]; sqj[t] = sq[g];
                } else {
                    jidx[t] = -1; labj[t] = INT_MIN; sqj[t] = 0.f;
                }
            }
            __syncthreads();

            f32x4 acc0 = {0.f, 0.f, 0.f, 0.f}, acc1 = {0.f, 0.f, 0.f, 0.f};
#pragma unroll
            for (int st = 0; st < 4; ++st) {
                bf16x8 b0 = *(const bf16x8*)&Bs[jb0 + c][st * 32 + q * 8];
                acc0 = __builtin_amdgcn_mfma_f32_16x16x32_bf16(afr[st], b0, acc0, 0, 0, 0);
            }
#pragma unroll
            for (int st = 0; st < 4; ++st) {
                bf16x8 b1 = *(const bf16x8*)&Bs[jb0 + 16 + c][st * 32 + q * 8];
                acc1 = __builtin_amdgcn_mfma_f32_16x16x32_bf16(afr[st], b1, acc1, 0, 0, 0);
            }
            // ---- fused selection: lane's acc[r] is dot(E[i0+isub*16+q*4+r],
            //      E[grp[j0 + jb0 + sub*16 + c]])  (C/D: row=q*4+reg, col=lane&15)
#pragma unroll
            for (int sub = 0; sub < 2; ++sub) {
                int jl = jb0 + sub * 16 + c;
                int jj = jidx[jl];
                if (jj >= 0) {
                    int lj = labj[jl]; float sv = sqj[jl];
#pragma unroll
                    for (int r = 0; r < 4; ++r) {
                        float dotv = sub ? acc1[r] : acc0[r];
                        float v = fmaf(-2.f, dotv, sv);    // d2 minus row-const sq_i
                        if (lj == li[r]) {
                            if (jj != gI[r] && (v > vP[r] ||
                                (v == vP[r] && (unsigned)jj < (unsigned)iP[r]))) {
                                vP[r] = v; iP[r] = jj;
                            }
                        } else if (v < vN[r] ||
                                   (v == vN[r] && (unsigned)jj < (unsigned)iN[r])) {
                            vN[r] = v; iN[r] = jj;
                        }
                    }
                }
            }
            __syncthreads();                   // Bs consumed before restage
        }

        // ---- reduce over the 16 lanes sharing each i-row (shfl width 16) ----
#pragma unroll
        for (int off = 8; off > 0; off >>= 1) {
#pragma unroll
            for (int r = 0; r < 4; ++r) {
                float ov = __shfl_down(vP[r], off, 16);
                int   oi = __shfl_down(iP[r], off, 16);
                if (ov > vP[r] || (ov == vP[r] && (unsigned)oi < (unsigned)iP[r])) {
                    vP[r] = ov; iP[r] = oi;
                }
                float on = __shfl_down(vN[r], off, 16);
                int   oj = __shfl_down(iN[r], off, 16);
                if (on < vN[r] || (on == vN[r] && (unsigned)oj < (unsigned)iN[r])) {
                    vN[r] = on; iN[r] = oj;
                }
            }
        }
        if (c == 0) {
#pragma unroll
            for (int r = 0; r < 4; ++r) {
                int row = isub * 16 + q * 4 + r;
                svP[row][jhalf] = vP[r]; siP[row][jhalf] = iP[r];
                svN[row][jhalf] = vN[r]; siN[row][jhalf] = iN[r];
            }
        }
        __syncthreads();
        if (t < TI) {
            float bp = svP[t][0]; int ip = siP[t][0];
            float o  = svP[t][1]; int oi = siP[t][1];
            if (o > bp || (o == bp && (unsigned)oi < (unsigned)ip)) { bp = o; ip = oi; }
            float bn = svN[t][0]; int in_ = siN[t][0];
            float on = svN[t][1]; int oj = siN[t][1];
            if (on < bn || (on == bn && (unsigned)oj < (unsigned)in_)) { bn = on; in_ = oj; }
            selP[t] = ip; selN[t] = in_;
        }
        __syncthreads();

        // ---- exact fp32 distances: 8 threads per row ----
        {
            int row = t >> 3, u = t & 7;
            int p = selP[row], nn = selN[row], g = gi[row];
            bool valid = (row < nrows) && (p >= 0) && (nn >= 0);
            float sump = 0.f, sumn = 0.f;
            if (valid) {
                const float4* ai = (const float4*)(emb + (size_t)g * D);
                const float4* ep = (const float4*)(emb + (size_t)p * D);
                const float4* en = (const float4*)(emb + (size_t)nn * D);
#pragma unroll
                for (int z = 0; z < 4; ++z) {
                    int c4 = u * 4 + z;
                    float4 x = ai[c4], vp = ep[c4], vn = en[c4];
                    float d;
                    d = x.x - vp.x + EPS; sump = fmaf(d, d, sump);
                    d = x.y - vp.y + EPS; sump = fmaf(d, d, sump);
                    d = x.z - vp.z + EPS; sump = fmaf(d, d, sump);
                    d = x.w - vp.w + EPS; sump = fmaf(d, d, sump);
                    d = x.x - vn.x + EPS; sumn = fmaf(d, d, sumn);
                    d = x.y - vn.y + EPS; sumn = fmaf(d, d, sumn);
                    d = x.z - vn.z + EPS; sumn = fmaf(d, d, sumn);
                    d = x.w - vn.w + EPS; sumn = fmaf(d, d, sumn);
                }
            }
#pragma unroll
            for (int off = 4; off > 0; off >>= 1) {
                sump += __shfl_down(sump, off, 8);
                sumn += __shfl_down(sumn, off, 8);
            }
            if (u == 0) {
                perRow[row]   = valid ? fmaxf(sqrtf(sump) - sqrtf(sumn) + MARGIN, 0.f) : 0.f;
                validRow[row] = valid ? 1 : 0;
            }
        }
        __syncthreads();
        if (t == 0) {
#pragma unroll
            for (int r = 0; r < TI; ++r) { blockSum += perRow[r]; blockCnt += validRow[r]; }
        }
    }
    if (t == 0 && blockCnt > 0) {
        atomicAdd(loss_sum, blockSum);
        atomicAdd(valid_cnt, blockCnt);
    }
}

__global__ void finalize_kernel(const float* __restrict__ loss_sum,
                                const int* __restrict__ valid_cnt,
                                float* __restrict__ out) {
    float sum = *loss_sum;
    int cnt = *valid_cnt;
    out[0] = (cnt > 0) ? (sum / (float)cnt) : 0.0f;
}

extern "C" void kernel_launch(void* const* d_in, const int* in_sizes, int n_in,
                              void* d_out, int out_size, void* d_ws, size_t ws_size,
                              hipStream_t stream) {
    const float* emb    = (const float*)d_in[0];
    const int*   labels = (const int*)d_in[1];
    const int*   sbj    = (const int*)d_in[2];
    float*       out    = (float*)d_out;
    int B = in_sizes[1];   // 8192

    // Workspace layout:
    //   [0,64)    : int counts[16]
    //   [64,68)   : float loss_sum
    //   [72,76)   : int valid_cnt
    //   [128, 128+4B)   : float sq[B]
    //   [128+4B, ...)   : int lists[16][B]
    char*  ws        = (char*)d_ws;
    int*   counts    = (int*)ws;
    float* loss_sum  = (float*)(ws + 64);
    int*   valid_cnt = (int*)(ws + 72);
    float* sq        = (float*)(ws + 128);
    int*   lists     = (int*)(ws + 128 + (size_t)B * sizeof(float));

    hipMemsetAsync(ws, 0, 128, stream);
    prep_kernel<<<(B + 255) / 256, 256, 0, stream>>>(emb, sbj, sq, counts, lists, B);
    dim3 grid(GX, NSUBJ);
    triplet_mfma<<<grid, 256, 0, stream>>>(emb, labels, sq, counts, lists,
                                           loss_sum, valid_cnt, B);
    finalize_kernel<<<1, 1, 0, stream>>>(loss_sum, valid_cnt, out);
}